// Round 11
// baseline (152.332 us; speedup 1.0000x reference)
//
#include <hip/hip_runtime.h>
#include <hip/hip_bf16.h>

// Problem constants (fixed by the reference)
#define BATCH 8
#define NPTS  4096      // N
#define CCH   128      // C
#define KNN_K 16       // K

// KNN spatial grid: 16^3 cells over [-4.6, 4.6)^3 (N(0,1) outliers clamp)
#define GD  16
#define GC  (GD * GD * GD)      // 4096 cells per batch
#define GLO (-4.6f)
#define GH  (9.2f / 16.0f)      // 0.575
#define GIH (16.0f / 9.2f)

#define MAXTASK 40960           // >= 8 * (1024 + nonempty cells) upper bound

typedef __attribute__((ext_vector_type(8))) short  bf16x8;  // 8 bf16 = 4 VGPRs
typedef __attribute__((ext_vector_type(4))) float  f32x4;   // MFMA acc

// ---------------------------------------------------------------------------
// ws layout (bytes):
//   [0)          xTb   : B*N*C bf16      = 8,388,608
//   [8388608)    Wb    : C*C  bf16       =    32,768
//   [8421376)    scale : C fp32          =       512
//   [8421888)    bias  : C fp32          =       512
//   [8422400)    pts   : B*N float4(x,y,z,s) = 524,288
//   [8946688)    knn   : B*N*K u16       = 1,048,576
//   [9995264)    Zb    : B*N*C bf16      = 8,388,608   (Z = W@x, [B,N,C])
// Grid scratch OVERLAYS Zb (zgemm writes Zb only after knn completes):
//   Zb+0         counts : u32[8*GC]   = 131,072
//   Zb+131072    fill   : u32[8*GC]   = 131,072
//   Zb+262144    starts : u32[8*GC]   = 131,072
//   Zb+393216    cellid : u32[B*N]    = 131,072
//   Zb+524288    psort  : float4[B*N] = 524,288  (w = orig-index bits)
//   Zb+1048576   tasks  : u32[40960]  = 163,840
//   Zb+1212416   taskcnt: u32         (ends 1,212,420 < 8 MB)
// ---------------------------------------------------------------------------

static __device__ __forceinline__ short f2bf(float v) {
    __hip_bfloat16 h = __float2bfloat16(v);   // RNE
    return __builtin_bit_cast(short, h);
}

// LDS-tiled transpose: x [B,C,N] fp32 -> xTb [B,N,C] bf16.
__global__ __launch_bounds__(256) void transpose_kernel(
    const float* __restrict__ x, short* __restrict__ xTb)
{
    __shared__ short tile[64 * 66];
    const int tid = threadIdx.x;
    const int b   = blockIdx.x >> 7;         // 8 batches
    const int rem = blockIdx.x & 127;
    const int nt  = rem >> 1;                // 64 n-tiles of 64
    const int ct  = rem & 1;                 // 2 c-tiles of 64

    #pragma unroll
    for (int it = 0; it < 16; ++it) {
        const int idx = it * 256 + tid;
        const int cc  = idx >> 6;
        const int nn  = idx & 63;
        const float v = x[(size_t)(b * CCH + ct * 64 + cc) * NPTS + nt * 64 + nn];
        tile[cc * 66 + nn] = f2bf(v);
    }
    __syncthreads();
    #pragma unroll
    for (int it = 0; it < 16; ++it) {
        const int idx = it * 256 + tid;
        const int nn  = idx >> 6;
        const int cc  = idx & 63;
        xTb[(size_t)(b * NPTS + nt * 64 + nn) * CCH + ct * 64 + cc] = tile[cc * 66 + nn];
    }
}

// Small prep: W -> bf16; fold BN affine; xyz -> SoA float4 with |p|^2
__global__ __launch_bounds__(256) void small_prep_kernel(
    const float* __restrict__ xyz, const float* __restrict__ W,
    const float* __restrict__ gamma, const float* __restrict__ beta,
    const float* __restrict__ rmean, const float* __restrict__ rvar,
    short* __restrict__ Wb, float* __restrict__ scale, float* __restrict__ bias,
    float4* __restrict__ pts)
{
    const int t = blockIdx.x * 256 + threadIdx.x;   // grid covers B*N = 32768
    if (t < CCH * CCH) Wb[t] = f2bf(W[t]);
    if (t < CCH) {
        const float s = gamma[t] / sqrtf(rvar[t] + 1e-5f);
        scale[t] = s;
        bias[t]  = beta[t] - rmean[t] * s;
    }
    {
        #pragma clang fp contract(off)
        const float px = xyz[3 * t + 0];
        const float py = xyz[3 * t + 1];
        const float pz = xyz[3 * t + 2];
        const float s  = px * px + py * py + pz * pz;   // matches ref s = sum(xyz*xyz)
        pts[t] = make_float4(px, py, pz, s);
    }
}

// ---- grid build ----------------------------------------------------------

__global__ __launch_bounds__(256) void zero_kernel(uint4* __restrict__ p,
                                                   unsigned* __restrict__ taskcnt)
{
    p[blockIdx.x * 256 + threadIdx.x] = make_uint4(0, 0, 0, 0);  // counts+fill
    if (blockIdx.x == 0 && threadIdx.x == 0) *taskcnt = 0;
}

static __device__ __forceinline__ int cell_of(float v) {
    int c = (int)floorf((v - GLO) * GIH);
    return c < 0 ? 0 : (c > GD - 1 ? GD - 1 : c);
}

__global__ __launch_bounds__(256) void hist_kernel(
    const float4* __restrict__ pts, unsigned* __restrict__ counts,
    unsigned* __restrict__ cellid)
{
    const int t = blockIdx.x * 256 + threadIdx.x;   // B*N
    const float4 p = pts[t];
    const int cell = (cell_of(p.z) * GD + cell_of(p.y)) * GD + cell_of(p.x);
    cellid[t] = (unsigned)cell;
    atomicAdd(&counts[((t >> 12) << 12) + cell], 1u);
}

// exclusive scan of 4096 cell counts per batch (one block per batch) + task
// emission fused (one task per (cell, group of <=4 queries); order irrelevant)
__global__ __launch_bounds__(1024) void scan_kernel(
    const unsigned* __restrict__ counts, unsigned* __restrict__ starts,
    unsigned* __restrict__ tasks, unsigned* __restrict__ taskcnt)
{
    __shared__ unsigned part[1024];
    const int b = blockIdx.x, t = threadIdx.x;
    const int base = (b << 12) + t * 4;
    unsigned c0 = counts[base], c1 = counts[base + 1];
    unsigned c2 = counts[base + 2], c3 = counts[base + 3];
    part[t] = c0 + c1 + c2 + c3;
    __syncthreads();
    for (int off = 1; off < 1024; off <<= 1) {
        const unsigned v = (t >= off) ? part[t - off] : 0u;
        __syncthreads();
        part[t] += v;
        __syncthreads();
    }
    unsigned run = (t == 0) ? 0u : part[t - 1];
    starts[base]     = run; run += c0;
    starts[base + 1] = run; run += c1;
    starts[base + 2] = run; run += c2;
    starts[base + 3] = run;

    // emit tasks for this thread's 4 cells
    const unsigned n0 = (c0 + 3) >> 2, n1 = (c1 + 3) >> 2;
    const unsigned n2 = (c2 + 3) >> 2, n3 = (c3 + 3) >> 2;
    const unsigned nt = n0 + n1 + n2 + n3;
    if (nt) {
        unsigned pos = atomicAdd(taskcnt, nt);
        const unsigned hdr = ((unsigned)b << 19);
        for (unsigned i = 0; i < n0; ++i) tasks[pos++] = hdr | ((unsigned)(t*4+0) << 7) | i;
        for (unsigned i = 0; i < n1; ++i) tasks[pos++] = hdr | ((unsigned)(t*4+1) << 7) | i;
        for (unsigned i = 0; i < n2; ++i) tasks[pos++] = hdr | ((unsigned)(t*4+2) << 7) | i;
        for (unsigned i = 0; i < n3; ++i) tasks[pos++] = hdr | ((unsigned)(t*4+3) << 7) | i;
    }
}

// scatter: psort.w carries the ORIGINAL within-batch index (bit pattern);
// |p|^2 is recomputed in the knn kernel with the bit-identical expression.
__global__ __launch_bounds__(256) void scatter_kernel(
    const float4* __restrict__ pts, const unsigned* __restrict__ cellid,
    const unsigned* __restrict__ starts, unsigned* __restrict__ fill,
    float4* __restrict__ psort)
{
    const int t = blockIdx.x * 256 + threadIdx.x;   // B*N
    const unsigned idx = ((unsigned)(t >> 12) << 12) + cellid[t];
    const unsigned pos = starts[idx] + atomicAdd(&fill[idx], 1u);
    const int d = ((t >> 12) << 12) + (int)pos;
    const float4 p = pts[t];
    psort[d] = make_float4(p.x, p.y, p.z, __uint_as_float((unsigned)(t & 4095)));
}

// ---- grid KNN ------------------------------------------------------------

#define PK_(h, l) ((((unsigned long long)(h)) << 32) | (unsigned long long)(l))

// KNN v10: cell-homogeneous tasks (R9) + latency fixes:
//  - PERSISTENT WAVES: 8192 waves stride the task list (balanced tail).
//  - SINGLE-PHASE B1: 9 rows' (st,en) fetched by lanes 0..8 in one memory
//    round-trip, streamed as 9 spans; rings start at R=2.
//  - 32 CANDIDATES/ITER in stream: two back-to-back float4 loads (MLP=2),
//    two d2 computes, two appends.
// Selection machinery (append/sort16/flush, keys (mono(d2), orig_j)) is
// byte-identical to the R6-R9-verified version; d2 = (qs+cs) - 2*dot with
// the bit-identical contract-off reference expression. Candidates are seen
// exactly once (B1 rows + disjoint rings R>=2); per-query exact termination
// dmin^2(box R) > tau; rings cover the grid by R=15 -> completeness.
__global__ __launch_bounds__(256) void knn_grid_kernel(
    const float4* __restrict__ psort, const unsigned* __restrict__ starts,
    const unsigned* __restrict__ tasks, const unsigned* __restrict__ taskcnt,
    unsigned short* __restrict__ knn)
{
    const int lane = threadIdx.x & 63;
    const int wid  = threadIdx.x >> 6;
    const int g    = lane >> 4;                 // group (query) 0..3
    const int s    = lane & 15;                 // slot within group
    const int      gsh   = g << 4;
    const unsigned smask = (1u << s) - 1u;
    const unsigned SENT_HI = 0xFF7FFFFFu;       // mono(+3.4e38)
    const unsigned SENT_LO = 0xFFFFFFFFu;

    const unsigned tc = *taskcnt;
    const unsigned nwv = gridDim.x * 4;

    #pragma unroll 1
    for (unsigned tid = blockIdx.x * 4 + wid; tid < tc; tid += nwv) {
        const unsigned tk = tasks[tid];
        const int b    = (int)(tk >> 19);
        const int cell = (int)((tk >> 7) & 0xFFFu);
        const int sub  = (int)(tk & 0x7Fu);

        const float4*   ps  = psort + (b << 12);
        const unsigned* cst = starts + (b << 12);

        const unsigned cs0 = cst[cell];
        const unsigned ce0 = (cell == GC - 1) ? (unsigned)NPTS : cst[cell + 1];
        const int  ccnt = (int)(ce0 - cs0);
        const int  gpos = sub * 4 + g;
        const bool act  = gpos < ccnt;          // group-uniform
        const int  sp   = (int)cs0 + (act ? gpos : ccnt - 1);

        const float4 qp = ps[sp];               // group-uniform
        const int    qi = (int)__float_as_uint(qp.w);
        float qs;
        {
            #pragma clang fp contract(off)
            qs = qp.x * qp.x + qp.y * qp.y + qp.z * qp.z;   // == small_prep bits
        }

        const int hx = cell & 15, hy = (cell >> 4) & 15, hz = cell >> 8;
        const float hlx = GLO + hx * GH;
        const float hly = GLO + hy * GH;
        const float hlz = GLO + hz * GH;

        unsigned lhi = SENT_HI, llo = SENT_LO;  // sorted top-16 list (asc)
        float bufD = 0.f;                       // survivor buffer (slot s)
        int   bufJ = 0;
        int   cnt  = 0;                         // valid entries (group-uniform)
        float tau  = 3.4e38f;

        auto sort16 = [&](unsigned& hi, unsigned& lo) {
            #define CE_(K, J, OFF) { \
                const unsigned ohi = (unsigned)__builtin_amdgcn_ds_swizzle((int)hi, OFF); \
                const unsigned olo = (unsigned)__builtin_amdgcn_ds_swizzle((int)lo, OFF); \
                const bool olt = PK_(ohi, olo) < PK_(hi, lo); \
                const bool sel = (((s & (J)) == 0) == ((s & (K)) == 0)); \
                const bool tk2 = sel ? olt : !olt; \
                hi = tk2 ? ohi : hi; lo = tk2 ? olo : lo; }
            CE_(2, 1, 0x041F)
            CE_(4, 2, 0x081F)  CE_(4, 1, 0x041F)
            CE_(8, 4, 0x101F)  CE_(8, 2, 0x081F)  CE_(8, 1, 0x041F)
            CE_(16, 8, 0x201F) CE_(16, 4, 0x101F) CE_(16, 2, 0x081F) CE_(16, 1, 0x041F)
            #undef CE_
        };

        auto refresh_tau = [&]() {
            const unsigned thi = (unsigned)__builtin_amdgcn_ds_swizzle((int)lhi, 0x01F0);
            tau = __uint_as_float((thi & 0x80000000u) ? (thi & 0x7FFFFFFFu) : ~thi);
        };

        auto flush = [&]() {
            const unsigned u = __float_as_uint(bufD);
            unsigned khi = (u & 0x80000000u) ? ~u : (u | 0x80000000u);
            unsigned klo = (unsigned)bufJ;
            const bool inval = (s >= cnt);
            khi = inval ? SENT_HI : khi;
            klo = inval ? SENT_LO : klo;
            sort16(khi, klo);
            {
                const unsigned rhi = (unsigned)__builtin_amdgcn_ds_swizzle((int)khi, 0x3C1F);
                const unsigned rlo = (unsigned)__builtin_amdgcn_ds_swizzle((int)klo, 0x3C1F);
                const bool rlt = PK_(rhi, rlo) < PK_(lhi, llo);
                lhi = rlt ? rhi : lhi; llo = rlt ? rlo : llo;
            }
            #define MC_(J, OFF) { \
                const unsigned ohi = (unsigned)__builtin_amdgcn_ds_swizzle((int)lhi, OFF); \
                const unsigned olo = (unsigned)__builtin_amdgcn_ds_swizzle((int)llo, OFF); \
                const bool olt = PK_(ohi, olo) < PK_(lhi, llo); \
                const bool tk2 = ((s & (J)) == 0) ? olt : !olt; \
                lhi = tk2 ? ohi : lhi; llo = tk2 ? olo : llo; }
            MC_(8, 0x201F) MC_(4, 0x101F) MC_(2, 0x081F) MC_(1, 0x041F)
            #undef MC_
            refresh_tau();
            cnt = 0;
        };

        auto append = [&](float d2v, int jov) {
            const unsigned long long mask = __ballot(d2v <= tau);
            if (mask) {
                const unsigned sub2 = (unsigned)((mask >> gsh) & 0xFFFFull);
                const int m = __popc(sub2);
                const int lim = 15 + (m >> 4);  // m==16 needs no parking slot
                if (__any(cnt + m > lim)) flush();
                const bool surv = (sub2 >> s) & 1u;
                const int rank  = __popc(sub2 & smask);
                const int dest  = surv ? (cnt + rank) : 15;
                const int addr  = (gsh | dest) << 2;
                const int nd = __builtin_amdgcn_ds_permute(addr, __float_as_int(d2v));
                const int nj = __builtin_amdgcn_ds_permute(addr, jov);
                const bool got = (s >= cnt) & (s < cnt + m);
                bufD = got ? __int_as_float(nd) : bufD;
                bufJ = got ? nj : bufJ;
                cnt += m;
            }
        };

        // stream [st, en): 32 candidates/iteration, dual loads for MLP
        auto stream = [&](unsigned st, unsigned en) {
            unsigned c0 = st;
            for (; c0 + 16 < en; c0 += 32) {
                const unsigned i0 = c0 + (unsigned)s;          // always < en
                const unsigned i1 = i0 + 16;
                const bool v1 = i1 < en;
                const float4 p0 = ps[i0];
                const float4 p1 = ps[v1 ? i1 : i0];
                float d20, d21;
                {
                    #pragma clang fp contract(off)
                    const float cs0_ = p0.x * p0.x + p0.y * p0.y + p0.z * p0.z;
                    const float dt0  = qp.x * p0.x + qp.y * p0.y + qp.z * p0.z;
                    d20 = (qs + cs0_) - 2.0f * dt0;
                    const float cs1_ = p1.x * p1.x + p1.y * p1.y + p1.z * p1.z;
                    const float dt1  = qp.x * p1.x + qp.y * p1.y + qp.z * p1.z;
                    d21 = (qs + cs1_) - 2.0f * dt1;
                }
                d21 = v1 ? d21 : __builtin_inff();
                append(d20, (int)__float_as_uint(p0.w));
                append(d21, (int)__float_as_uint(p1.w));
            }
            if (c0 < en) {
                const unsigned idx = c0 + (unsigned)s;
                float d2 = __builtin_inff();
                int   jo = 0;
                if (idx < en) {
                    const float4 p = ps[idx];
                    jo = (int)__float_as_uint(p.w);
                    {
                        #pragma clang fp contract(off)
                        const float cs_ = p.x * p.x + p.y * p.y + p.z * p.z;
                        const float dt  = qp.x * p.x + qp.y * p.y + qp.z * p.z;
                        d2 = (qs + cs_) - 2.0f * dt;
                    }
                }
                append(d2, jo);
            }
        };

        // squared lower bound on distance from q to anything OUTSIDE box B_R
        auto dmin2_box = [&](int R) -> float {
            const float e  = (float)R * GH;
            const float m1 = fminf(qp.x - (hlx - e), (hlx + GH + e) - qp.x);
            const float m2 = fminf(qp.y - (hly - e), (hly + GH + e) - qp.y);
            const float m3 = fminf(qp.z - (hlz - e), (hlz + GH + e) - qp.z);
            const float dm = fmaxf(fminf(m1, fminf(m2, m3)) - 1e-4f, 0.f);
            return dm * dm;
        };

        // ---- B1 (home + ring1) as 9 full-row spans, metadata via lanes 0..8
        {
            const int x0 = max(hx - 1, 0), x1 = min(hx + 1, GD - 1);
            unsigned rst = 0, ren = 0; int rok = 0;
            if (lane < 9) {
                const int zz = hz + lane / 3 - 1;
                const int yy = hy + lane % 3 - 1;
                if ((unsigned)zz < GD && (unsigned)yy < GD) {
                    const int cb = (zz * GD + yy) * GD;
                    rst = cst[cb + x0];
                    ren = (cb + x1 + 1 < GC) ? cst[cb + x1 + 1] : (unsigned)NPTS;
                    rok = 1;
                }
            }
            #pragma unroll 1
            for (int r = 0; r < 9; ++r)
                if (__shfl(rok, r)) stream(__shfl(rst, r), __shfl(ren, r));
        }
        if (__any(cnt != 0)) flush();

        // ---- expanding rings R>=2 with exact per-query termination
        if (!__all(dmin2_box(1) > tau)) {
            #pragma unroll 1
            for (int R = 2; R <= 15; ++R) {
                const int W = 2 * R + 1;
                const int nrows = W * W;
                const int x0 = max(hx - R, 0), x1 = min(hx + R, GD - 1);
                for (int base = 0; base < nrows; base += 64) {
                    unsigned fst = 0, fen = 0, lst = 0, len = 0, rst = 0, ren = 0;
                    int kind = 0;               // 0=skip, 1=full row, 2=two singles
                    const int row = base + lane;
                    if (row < nrows) {
                        const int dz = row / W - R, dy = row % W - R;
                        const int zz = hz + dz, yy = hy + dy;
                        if ((unsigned)zz < GD && (unsigned)yy < GD) {
                            const int cb = (zz * GD + yy) * GD;
                            const bool full = (dz == -R) | (dz == R) | (dy == -R) | (dy == R);
                            if (full) {
                                kind = 1;
                                fst = cst[cb + x0];
                                fen = (cb + x1 + 1 < GC) ? cst[cb + x1 + 1] : (unsigned)NPTS;
                            } else {
                                kind = 2;
                                if (hx - R >= 0) {
                                    lst = cst[cb + hx - R];
                                    len = cst[cb + hx - R + 1];
                                }
                                if (hx + R <= GD - 1) {
                                    rst = cst[cb + hx + R];
                                    ren = (cb + hx + R + 1 < GC) ? cst[cb + hx + R + 1] : (unsigned)NPTS;
                                }
                            }
                        }
                    }
                    const int lim = (nrows - base < 64) ? (nrows - base) : 64;
                    #pragma unroll 1
                    for (int r = 0; r < lim; ++r) {
                        const int k = __shfl(kind, r);
                        if (k == 1) {
                            stream(__shfl(fst, r), __shfl(fen, r));
                        } else if (k == 2) {
                            const unsigned sa = __shfl(lst, r), sb = __shfl(len, r);
                            if (sa < sb) stream(sa, sb);
                            const unsigned sc = __shfl(rst, r), sd = __shfl(ren, r);
                            if (sc < sd) stream(sc, sd);
                        }
                    }
                }
                if (__any(cnt != 0)) flush();
                if (__all(dmin2_box(R) > tau)) break;
            }
        }
        if (__any(cnt != 0)) flush();           // safety drain

        if (act) {
            unsigned short* o = knn + ((((size_t)b << 12) + qi) << 4);
            o[s] = (unsigned short)llo;         // j of s-th smallest (d2, j)
        }
    }
}

// Dense GEMM: Z[g, c] = sum_k xTb[g, k] * W[c, k], Z bf16 [B*N, C].
__global__ __launch_bounds__(256) void zgemm_kernel(
    const short* __restrict__ xTb, const short* __restrict__ Wb,
    short* __restrict__ Zb)
{
    __shared__ short sW[CCH * 136];
    const int lane = threadIdx.x & 63;
    const int wid  = threadIdx.x >> 6;
    const int kl   = lane & 15;
    const int q8   = (lane >> 4) * 8;

    #pragma unroll
    for (int it = 0; it < 8; ++it) {             // stage W: 16384 elems
        const int e = (it * 256 + threadIdx.x) * 8;
        const int r = e >> 7, c = e & 127;
        *(bf16x8*)(sW + r * 136 + c) = *(const bf16x8*)(Wb + e);
    }

    const int    G    = blockIdx.x * 64 + wid * 16 + kl;   // A-row (flat B*N)
    const size_t arow = (size_t)G * CCH;
    __syncthreads();

    const f32x4 zero = {0.f, 0.f, 0.f, 0.f};
    f32x4 acc[8];
    #pragma unroll
    for (int t = 0; t < 8; ++t) acc[t] = zero;

    #pragma unroll
    for (int kk = 0; kk < 4; ++kk) {
        const bf16x8 a = *(const bf16x8*)(xTb + arow + kk * 32 + q8);
        #pragma unroll
        for (int t = 0; t < 8; ++t) {
            const bf16x8 bf = *(const bf16x8*)(sW + (t * 16 + kl) * 136 + kk * 32 + q8);
            acc[t] = __builtin_amdgcn_mfma_f32_16x16x32_bf16(a, bf, acc[t], 0, 0, 0);
        }
    }

    const int rbase = blockIdx.x * 64 + wid * 16 + (lane >> 4) * 4;
    #pragma unroll
    for (int t = 0; t < 8; ++t)
        #pragma unroll
        for (int r = 0; r < 4; ++r)
            Zb[(size_t)(rbase + r) * CCH + t * 16 + kl] = f2bf(acc[t][r]);
}

// Gather + BN + ReLU + max-over-16, then coalesced store via LDS transpose.
__global__ __launch_bounds__(256) void gmax_kernel(
    const short* __restrict__ Zb, const unsigned short* __restrict__ knn,
    const float* __restrict__ scale, const float* __restrict__ bias,
    float* __restrict__ out)
{
    __shared__ float sm[16][132];
    const int lane = threadIdx.x & 63;
    const int wid  = threadIdx.x >> 6;
    const int n0   = blockIdx.x * 16;           // flat point base (B*N)
    const int b    = blockIdx.x >> 8;           // 256 blocks per batch
    const float s0 = scale[2 * lane],   s1 = scale[2 * lane + 1];
    const float t0 = bias[2 * lane],    t1 = bias[2 * lane + 1];

    for (int p = 0; p < 4; ++p) {
        const int n = n0 + wid * 4 + p;         // flat
        const unsigned short* kr = knn + (size_t)n * 16;
        float m0 = 0.f, m1 = 0.f;               // relu floor
        #pragma unroll
        for (int k = 0; k < 16; ++k) {
            const int r = (int)kr[k];           // within-batch row
            const unsigned v = *(const unsigned*)(Zb + ((size_t)(b * NPTS + r)) * CCH + 2 * lane);
            const float z0 = __uint_as_float(v << 16);
            const float z1 = __uint_as_float(v & 0xFFFF0000u);
            m0 = fmaxf(m0, s0 * z0 + t0);
            m1 = fmaxf(m1, s1 * z1 + t1);
        }
        sm[wid * 4 + p][2 * lane]     = m0;
        sm[wid * 4 + p][2 * lane + 1] = m1;
    }
    __syncthreads();

    const int c    = threadIdx.x & 127;
    const int half = threadIdx.x >> 7;
    float v[8];
    #pragma unroll
    for (int i = 0; i < 8; ++i) v[i] = sm[half * 8 + i][c];
    float4 f0 = {v[0], v[1], v[2], v[3]};
    float4 f1 = {v[4], v[5], v[6], v[7]};
    float* op = out + ((size_t)(b * CCH + c)) * NPTS + (n0 & 4095) + half * 8;
    *(float4*)op       = f0;
    *(float4*)(op + 4) = f1;
}

extern "C" void kernel_launch(void* const* d_in, const int* in_sizes, int n_in,
                              void* d_out, int out_size, void* d_ws, size_t ws_size,
                              hipStream_t stream)
{
    const float* xyz   = (const float*)d_in[0];
    const float* x     = (const float*)d_in[1];
    const float* W     = (const float*)d_in[2];
    const float* gamma = (const float*)d_in[3];
    const float* beta  = (const float*)d_in[4];
    const float* rmean = (const float*)d_in[5];
    const float* rvar  = (const float*)d_in[6];
    float* out = (float*)d_out;

    char* ws = (char*)d_ws;
    short*          xTb   = (short*)(ws);
    short*          Wb    = (short*)(ws + 8388608);
    float*          scale = (float*)(ws + 8421376);
    float*          bias  = (float*)(ws + 8421888);
    float4*         pts   = (float4*)(ws + 8422400);
    unsigned short* knn   = (unsigned short*)(ws + 8946688);
    short*          Zb    = (short*)(ws + 9995264);

    // grid scratch overlays Zb (consumed before zgemm writes Zb)
    char* gz = (char*)Zb;
    unsigned*       counts  = (unsigned*)(gz);
    unsigned*       fill    = (unsigned*)(gz + 131072);
    unsigned*       starts  = (unsigned*)(gz + 262144);
    unsigned*       cellid  = (unsigned*)(gz + 393216);
    float4*         psort   = (float4*)(gz + 524288);
    unsigned*       tasks   = (unsigned*)(gz + 1048576);
    unsigned*       taskcnt = (unsigned*)(gz + 1212416);

    transpose_kernel<<<BATCH * 64 * 2, 256, 0, stream>>>(x, xTb);
    small_prep_kernel<<<BATCH * NPTS / 256, 256, 0, stream>>>(
        xyz, W, gamma, beta, rmean, rvar, Wb, scale, bias, pts);
    zero_kernel<<<64, 256, 0, stream>>>((uint4*)gz, taskcnt);
    hist_kernel<<<BATCH * NPTS / 256, 256, 0, stream>>>(pts, counts, cellid);
    scan_kernel<<<BATCH, 1024, 0, stream>>>(counts, starts, tasks, taskcnt);
    scatter_kernel<<<BATCH * NPTS / 256, 256, 0, stream>>>(
        pts, cellid, starts, fill, psort);
    knn_grid_kernel<<<2048, 256, 0, stream>>>(psort, starts, tasks, taskcnt, knn);
    zgemm_kernel<<<BATCH * NPTS / 64, 256, 0, stream>>>(xTb, Wb, Zb);
    gmax_kernel<<<BATCH * NPTS / 16, 256, 0, stream>>>(Zb, knn, scale, bias, out);
}

// Round 12
// 112.770 us; speedup vs baseline: 1.3508x; 1.3508x over previous
//
#include <hip/hip_runtime.h>
#include <hip/hip_bf16.h>

// Problem constants (fixed by the reference)
#define BATCH 8
#define NPTS  4096      // N
#define CCH   128      // C
#define KNN_K 16       // K

typedef __attribute__((ext_vector_type(8))) short  bf16x8;  // 8 bf16 = 4 VGPRs
typedef __attribute__((ext_vector_type(4))) float  f32x4;   // MFMA acc

// ---------------------------------------------------------------------------
// ws layout (bytes):
//   [0)          xTb   : B*N*C bf16      = 8,388,608
//   [8388608)    Wb    : C*C  bf16       =    32,768
//   [8421376)    scale : C fp32          =       512
//   [8421888)    bias  : C fp32          =       512
//   [8422400)    pts   : B*N float4(x,y,z,s) = 524,288
//   [8946688)    knn   : B*N*K u16       = 1,048,576
//   [9995264)    Zb    : B*N*C bf16      = 8,388,608   (Z = W@x, [B,N,C])
// total 18,383,872
// ---------------------------------------------------------------------------

static __device__ __forceinline__ short f2bf(float v) {
    __hip_bfloat16 h = __float2bfloat16(v);   // RNE
    return __builtin_bit_cast(short, h);
}

// LDS-tiled transpose: x [B,C,N] fp32 -> xTb [B,N,C] bf16.
// v2: vectorized global sides — float4 loads (4 n per load), bf16x8 stores
// (8 c per store) via a [nn][cc] tile with pitch 72 (rows 16B-aligned).
__global__ __launch_bounds__(256) void transpose_kernel(
    const float* __restrict__ x, short* __restrict__ xTb)
{
    __shared__ short tile[64 * 72];          // [nn][cc], pitch 72 shorts
    const int tid = threadIdx.x;
    const int b   = blockIdx.x >> 7;         // 8 batches
    const int rem = blockIdx.x & 127;
    const int nt  = rem >> 1;                // 64 n-tiles of 64
    const int ct  = rem & 1;                 // 2 c-tiles of 64

    // phase 1: float4 along n, transpose into tile[nn][cc]
    #pragma unroll
    for (int it = 0; it < 4; ++it) {
        const int idx = it * 256 + tid;      // 0..1023
        const int cc  = idx >> 4;            // 0..63
        const int nf  = idx & 15;            // float4 index along n
        const float4 v = *(const float4*)(
            x + (size_t)(b * CCH + ct * 64 + cc) * NPTS + nt * 64 + nf * 4);
        tile[(nf * 4 + 0) * 72 + cc] = f2bf(v.x);
        tile[(nf * 4 + 1) * 72 + cc] = f2bf(v.y);
        tile[(nf * 4 + 2) * 72 + cc] = f2bf(v.z);
        tile[(nf * 4 + 3) * 72 + cc] = f2bf(v.w);
    }
    __syncthreads();
    // phase 2: bf16x8 along c (16B-aligned in tile and in xTb)
    #pragma unroll
    for (int it = 0; it < 2; ++it) {
        const int idx = it * 256 + tid;      // 0..511
        const int nn  = idx >> 3;            // 0..63
        const int c8  = idx & 7;             // 0..7
        const bf16x8 o = *(const bf16x8*)(tile + nn * 72 + c8 * 8);
        *(bf16x8*)(xTb + (size_t)(b * NPTS + nt * 64 + nn) * CCH + ct * 64 + c8 * 8) = o;
    }
}

// Small prep: W -> bf16; fold BN affine; xyz -> SoA float4 with |p|^2
__global__ __launch_bounds__(256) void small_prep_kernel(
    const float* __restrict__ xyz, const float* __restrict__ W,
    const float* __restrict__ gamma, const float* __restrict__ beta,
    const float* __restrict__ rmean, const float* __restrict__ rvar,
    short* __restrict__ Wb, float* __restrict__ scale, float* __restrict__ bias,
    float4* __restrict__ pts)
{
    const int t = blockIdx.x * 256 + threadIdx.x;   // grid covers B*N = 32768
    if (t < CCH * CCH) Wb[t] = f2bf(W[t]);
    if (t < CCH) {
        const float s = gamma[t] / sqrtf(rvar[t] + 1e-5f);
        scale[t] = s;
        bias[t]  = beta[t] - rmean[t] * s;
    }
    {
        #pragma clang fp contract(off)
        const float px = xyz[3 * t + 0];
        const float py = xyz[3 * t + 1];
        const float pz = xyz[3 * t + 2];
        const float s  = px * px + py * py + pz * pz;   // matches ref s = sum(xyz*xyz)
        pts[t] = make_float4(px, py, pz, s);
    }
}

#define PK_(h, l) ((((unsigned long long)(h)) << 32) | (unsigned long long)(l))

// KNN v4 (R4-verified dense kernel, byte-identical revert — best measured:
// 87 us, VALUBusy 87%). Buffered top-k with bitonic flush:
//  - manual A/C double-buffered candidate registers (no rotation moves)
//  - block 0 special case: first 16 candidates bitonic-sorted directly
//    into the list (kills tau=inf warm-up appends/flushes)
// Selection semantics == reference top_k: 16 smallest by (d2, j) lex,
// emitted in lex order. See R2 comments for the exactness argument.
__global__ __launch_bounds__(256) void knn_kernel(
    const float4* __restrict__ pts, unsigned short* __restrict__ knn)
{
    const int lane = threadIdx.x & 63;
    const int wid  = threadIdx.x >> 6;
    const int g    = lane >> 4;                 // group (query) 0..3
    const int s    = lane & 15;                 // slot within group
    const int wq   = blockIdx.x * 16 + wid * 4; // first query of this wave
    const int b    = wq >> 12;                  // 4 queries never cross a batch
    const int i    = (wq & 4095) + g;           // this lane's query
    const float4* pb = pts + (b << 12);

    const float4 q = pb[i];                     // group-uniform

    const unsigned SENT_HI = 0xFF7FFFFFu;       // mono(+3.4e38)
    const unsigned SENT_LO = 0xFFFFFFFFu;

    unsigned lhi = SENT_HI, llo = SENT_LO;      // sorted top-16 list (asc)
    float bufD = 0.f;                           // survivor buffer (slot s)
    int   bufJ = 0;
    int   cnt  = 0;                             // valid entries (group-uniform)
    float tau  = 3.4e38f;
    const int gsh = g << 4;

    // ascending bitonic sort of (hi,lo) keys across the 16 group lanes
    auto sort16 = [&](unsigned& hi, unsigned& lo) {
        #define CE_(K, J, OFF) { \
            const unsigned ohi = (unsigned)__builtin_amdgcn_ds_swizzle((int)hi, OFF); \
            const unsigned olo = (unsigned)__builtin_amdgcn_ds_swizzle((int)lo, OFF); \
            const bool olt = PK_(ohi, olo) < PK_(hi, lo); \
            const bool sel = (((s & (J)) == 0) == ((s & (K)) == 0)); \
            const bool tk  = sel ? olt : !olt; \
            hi = tk ? ohi : hi; lo = tk ? olo : lo; }
        CE_(2, 1, 0x041F)
        CE_(4, 2, 0x081F)  CE_(4, 1, 0x041F)
        CE_(8, 4, 0x101F)  CE_(8, 2, 0x081F)  CE_(8, 1, 0x041F)
        CE_(16, 8, 0x201F) CE_(16, 4, 0x101F) CE_(16, 2, 0x081F) CE_(16, 1, 0x041F)
        #undef CE_
    };

    // tau = inv-mono(list[15].hi)  (broadcast slot 15 within each 16-group)
    auto refresh_tau = [&]() {
        const unsigned thi = (unsigned)__builtin_amdgcn_ds_swizzle((int)lhi, 0x01F0);
        tau = __uint_as_float((thi & 0x80000000u) ? (thi & 0x7FFFFFFFu) : ~thi);
    };

    auto flush = [&]() {
        // build keys from buffer; invalid slots -> sentinel
        const unsigned u = __float_as_uint(bufD);
        unsigned khi = (u & 0x80000000u) ? ~u : (u | 0x80000000u);
        unsigned klo = (unsigned)bufJ;
        const bool inval = (s >= cnt);
        khi = inval ? SENT_HI : khi;
        klo = inval ? SENT_LO : klo;
        sort16(khi, klo);
        // merge with list: reverse buffer, elementwise min, 4 clean stages
        {
            const unsigned rhi = (unsigned)__builtin_amdgcn_ds_swizzle((int)khi, 0x3C1F);
            const unsigned rlo = (unsigned)__builtin_amdgcn_ds_swizzle((int)klo, 0x3C1F);
            const bool rlt = PK_(rhi, rlo) < PK_(lhi, llo);
            lhi = rlt ? rhi : lhi; llo = rlt ? rlo : llo;
        }
        #define MC_(J, OFF) { \
            const unsigned ohi = (unsigned)__builtin_amdgcn_ds_swizzle((int)lhi, OFF); \
            const unsigned olo = (unsigned)__builtin_amdgcn_ds_swizzle((int)llo, OFF); \
            const bool olt = PK_(ohi, olo) < PK_(lhi, llo); \
            const bool tk  = ((s & (J)) == 0) ? olt : !olt; \
            lhi = tk ? ohi : lhi; llo = tk ? olo : llo; }
        MC_(8, 0x201F) MC_(4, 0x101F) MC_(2, 0x081F) MC_(1, 0x041F)
        #undef MC_
        refresh_tau();
        cnt = 0;
    };

    // filter + parallel append for one 16-candidate sub-chunk
    #define SUB_(DD, C, JB) { \
        const unsigned long long mask = __ballot((DD) < tau); \
        if (mask) { \
            const unsigned sub = (unsigned)((mask >> gsh) & 0xFFFFull); \
            const int m = __popc(sub); \
            if (__any(cnt + m > 15)) flush(); \
            const bool surv = (sub >> s) & 1u; \
            const int rank  = __popc(sub & ((1u << s) - 1u)); \
            const int dest  = surv ? (cnt + rank) : 15;   /* slot 15 free when m<16 */ \
            const int addr  = (gsh | dest) << 2; \
            const int nd = __builtin_amdgcn_ds_permute(addr, __float_as_int(DD)); \
            const int nj = __builtin_amdgcn_ds_permute(addr, (JB) + ((C) << 4) + s); \
            const bool got = (s >= cnt) & (s < cnt + m); \
            bufD = got ? __int_as_float(nd) : bufD; \
            bufJ = got ? nj : bufJ; \
            cnt += m; \
        } }

    // process one 64-candidate block (4 sub-chunks of 16)
    auto process = [&](const float4& p0, const float4& p1,
                       const float4& p2, const float4& p3, const int jbase) {
        float dd0, dd1, dd2, dd3;
        {
            #pragma clang fp contract(off)
            dd0 = (q.w + p0.w) - 2.0f * (q.x * p0.x + q.y * p0.y + q.z * p0.z);
            dd1 = (q.w + p1.w) - 2.0f * (q.x * p1.x + q.y * p1.y + q.z * p1.z);
            dd2 = (q.w + p2.w) - 2.0f * (q.x * p2.x + q.y * p2.y + q.z * p2.z);
            dd3 = (q.w + p3.w) - 2.0f * (q.x * p3.x + q.y * p3.y + q.z * p3.z);
        }
        SUB_(dd0, 0, jbase)
        SUB_(dd1, 1, jbase)
        SUB_(dd2, 2, jbase)
        SUB_(dd3, 3, jbase)
    };

    const float4* lp = pb + s;
    // block 0 into A, block 1 into C
    float4 a0 = lp[0],  a1 = lp[16],  a2 = lp[32],  a3 = lp[48];
    float4 c0 = lp[64], c1 = lp[80],  c2 = lp[96],  c3 = lp[112];

    // ---- special block 0: sort first sub-chunk (j = s) directly into list
    {
        float dd0, dd1, dd2, dd3;
        {
            #pragma clang fp contract(off)
            dd0 = (q.w + a0.w) - 2.0f * (q.x * a0.x + q.y * a0.y + q.z * a0.z);
            dd1 = (q.w + a1.w) - 2.0f * (q.x * a1.x + q.y * a1.y + q.z * a1.z);
            dd2 = (q.w + a2.w) - 2.0f * (q.x * a2.x + q.y * a2.y + q.z * a2.z);
            dd3 = (q.w + a3.w) - 2.0f * (q.x * a3.x + q.y * a3.y + q.z * a3.z);
        }
        const unsigned u = __float_as_uint(dd0);
        lhi = (u & 0x80000000u) ? ~u : (u | 0x80000000u);
        llo = (unsigned)s;                      // j = s for sub-chunk 0
        sort16(lhi, llo);
        refresh_tau();
        SUB_(dd1, 1, 0)
        SUB_(dd2, 2, 0)
        SUB_(dd3, 3, 0)
    }

    // ---- main loop: blocks 1..62 double-buffered, 63 peeled
    #pragma unroll 1
    for (int t = 0; t < 31; ++t) {
        const int blk = 1 + 2 * t;              // C holds block blk
        const float4* p2 = lp + (blk + 1) * 64; // prefetch blk+1 into A
        a0 = p2[0]; a1 = p2[16]; a2 = p2[32]; a3 = p2[48];
        process(c0, c1, c2, c3, blk * 64);
        const float4* p3 = lp + (blk + 2) * 64; // prefetch blk+2 into C (max 63)
        c0 = p3[0]; c1 = p3[16]; c2 = p3[32]; c3 = p3[48];
        process(a0, a1, a2, a3, (blk + 1) * 64);
    }
    process(c0, c1, c2, c3, 63 * 64);           // C holds block 63
    #undef SUB_

    flush();                                    // drain remaining buffer

    unsigned short* o = knn + ((((size_t)b << 12) + i) << 4);
    o[s] = (unsigned short)llo;                 // j of s-th smallest (d2, j)
}

// Dense GEMM: Z[g, c] = sum_k xTb[g, k] * W[c, k], Z bf16 [B*N, C].
// Wave = 16 rows x 128 cols; verified fragment mappings (A: m=lane&15,
// k=(lane>>4)*8+j; B: n=lane&15, same k-slice; C/D: col=lane&15,
// row=(lane>>4)*4+reg). W staged in LDS, pitch 136.
__global__ __launch_bounds__(256) void zgemm_kernel(
    const short* __restrict__ xTb, const short* __restrict__ Wb,
    short* __restrict__ Zb)
{
    __shared__ short sW[CCH * 136];
    const int lane = threadIdx.x & 63;
    const int wid  = threadIdx.x >> 6;
    const int kl   = lane & 15;
    const int q8   = (lane >> 4) * 8;

    #pragma unroll
    for (int it = 0; it < 8; ++it) {             // stage W: 16384 elems
        const int e = (it * 256 + threadIdx.x) * 8;
        const int r = e >> 7, c = e & 127;
        *(bf16x8*)(sW + r * 136 + c) = *(const bf16x8*)(Wb + e);
    }

    const int    G    = blockIdx.x * 64 + wid * 16 + kl;   // A-row (flat B*N)
    const size_t arow = (size_t)G * CCH;
    __syncthreads();

    const f32x4 zero = {0.f, 0.f, 0.f, 0.f};
    f32x4 acc[8];
    #pragma unroll
    for (int t = 0; t < 8; ++t) acc[t] = zero;

    #pragma unroll
    for (int kk = 0; kk < 4; ++kk) {
        const bf16x8 a = *(const bf16x8*)(xTb + arow + kk * 32 + q8);
        #pragma unroll
        for (int t = 0; t < 8; ++t) {
            const bf16x8 bf = *(const bf16x8*)(sW + (t * 16 + kl) * 136 + kk * 32 + q8);
            acc[t] = __builtin_amdgcn_mfma_f32_16x16x32_bf16(a, bf, acc[t], 0, 0, 0);
        }
    }

    const int rbase = blockIdx.x * 64 + wid * 16 + (lane >> 4) * 4;
    #pragma unroll
    for (int t = 0; t < 8; ++t)
        #pragma unroll
        for (int r = 0; r < 4; ++r)
            Zb[(size_t)(rbase + r) * CCH + t * 16 + kl] = f2bf(acc[t][r]);
}

// Gather + BN + ReLU + max-over-16, then coalesced store via LDS transpose.
// Block = 16 points; wave w handles 4 points serially; lane l covers channels
// 2l, 2l+1. v2: neighbor indices loaded as 2x uint4 up front so the 16 Zb
// row loads issue independently (were 16 dependent scalar u16 loads).
__global__ __launch_bounds__(256) void gmax_kernel(
    const short* __restrict__ Zb, const unsigned short* __restrict__ knn,
    const float* __restrict__ scale, const float* __restrict__ bias,
    float* __restrict__ out)
{
    __shared__ float sm[16][132];
    const int lane = threadIdx.x & 63;
    const int wid  = threadIdx.x >> 6;
    const int n0   = blockIdx.x * 16;           // flat point base (B*N)
    const int b    = blockIdx.x >> 8;           // 256 blocks per batch
    const float s0 = scale[2 * lane],   s1 = scale[2 * lane + 1];
    const float t0 = bias[2 * lane],    t1 = bias[2 * lane + 1];

    for (int p = 0; p < 4; ++p) {
        const int n = n0 + wid * 4 + p;         // flat
        const unsigned short* kr = knn + (size_t)n * 16;
        int ridx[16];
        {
            const uint4 ka = *(const uint4*)kr;        // 32B-aligned
            const uint4 kb = *(const uint4*)(kr + 8);
            ridx[0] = ka.x & 0xFFFF; ridx[1] = ka.x >> 16;
            ridx[2] = ka.y & 0xFFFF; ridx[3] = ka.y >> 16;
            ridx[4] = ka.z & 0xFFFF; ridx[5] = ka.z >> 16;
            ridx[6] = ka.w & 0xFFFF; ridx[7] = ka.w >> 16;
            ridx[8]  = kb.x & 0xFFFF; ridx[9]  = kb.x >> 16;
            ridx[10] = kb.y & 0xFFFF; ridx[11] = kb.y >> 16;
            ridx[12] = kb.z & 0xFFFF; ridx[13] = kb.z >> 16;
            ridx[14] = kb.w & 0xFFFF; ridx[15] = kb.w >> 16;
        }
        float m0 = 0.f, m1 = 0.f;               // relu floor
        #pragma unroll
        for (int k = 0; k < 16; ++k) {
            const unsigned v = *(const unsigned*)(
                Zb + ((size_t)(b * NPTS + ridx[k])) * CCH + 2 * lane);
            const float z0 = __uint_as_float(v << 16);
            const float z1 = __uint_as_float(v & 0xFFFF0000u);
            m0 = fmaxf(m0, s0 * z0 + t0);
            m1 = fmaxf(m1, s1 * z1 + t1);
        }
        sm[wid * 4 + p][2 * lane]     = m0;
        sm[wid * 4 + p][2 * lane + 1] = m1;
    }
    __syncthreads();

    const int c    = threadIdx.x & 127;
    const int half = threadIdx.x >> 7;
    float v[8];
    #pragma unroll
    for (int i = 0; i < 8; ++i) v[i] = sm[half * 8 + i][c];
    float4 f0 = {v[0], v[1], v[2], v[3]};
    float4 f1 = {v[4], v[5], v[6], v[7]};
    float* op = out + ((size_t)(b * CCH + c)) * NPTS + (n0 & 4095) + half * 8;
    *(float4*)op       = f0;
    *(float4*)(op + 4) = f1;
}

extern "C" void kernel_launch(void* const* d_in, const int* in_sizes, int n_in,
                              void* d_out, int out_size, void* d_ws, size_t ws_size,
                              hipStream_t stream)
{
    const float* xyz   = (const float*)d_in[0];
    const float* x     = (const float*)d_in[1];
    const float* W     = (const float*)d_in[2];
    const float* gamma = (const float*)d_in[3];
    const float* beta  = (const float*)d_in[4];
    const float* rmean = (const float*)d_in[5];
    const float* rvar  = (const float*)d_in[6];
    float* out = (float*)d_out;

    char* ws = (char*)d_ws;
    short*          xTb   = (short*)(ws);
    short*          Wb    = (short*)(ws + 8388608);
    float*          scale = (float*)(ws + 8421376);
    float*          bias  = (float*)(ws + 8421888);
    float4*         pts   = (float4*)(ws + 8422400);
    unsigned short* knn   = (unsigned short*)(ws + 8946688);
    short*          Zb    = (short*)(ws + 9995264);

    transpose_kernel<<<BATCH * 64 * 2, 256, 0, stream>>>(x, xTb);
    small_prep_kernel<<<BATCH * NPTS / 256, 256, 0, stream>>>(
        xyz, W, gamma, beta, rmean, rvar, Wb, scale, bias, pts);
    knn_kernel<<<BATCH * NPTS / 16, 256, 0, stream>>>(pts, knn);
    zgemm_kernel<<<BATCH * NPTS / 64, 256, 0, stream>>>(xTb, Wb, Zb);
    gmax_kernel<<<BATCH * NPTS / 16, 256, 0, stream>>>(Zb, knn, scale, bias, out);
}

// Round 13
// 110.772 us; speedup vs baseline: 1.3752x; 1.0180x over previous
//
#include <hip/hip_runtime.h>
#include <hip/hip_bf16.h>

// Problem constants (fixed by the reference)
#define BATCH 8
#define NPTS  4096      // N
#define CCH   128      // C
#define KNN_K 16       // K

typedef __attribute__((ext_vector_type(8))) short  bf16x8;  // 8 bf16 = 4 VGPRs
typedef __attribute__((ext_vector_type(4))) float  f32x4;   // MFMA acc

// ---------------------------------------------------------------------------
// ws layout (bytes):
//   [0)          (unused; was xTb)      = 8,388,608
//   [8388608)    Wb    : C*C  bf16      =    32,768
//   [8421376)    scale : C fp32         =       512
//   [8421888)    bias  : C fp32         =       512
//   [8422400)    pts   : B*N float4(x,y,z,s) = 524,288
//   [8946688)    knn   : B*N*K u16      = 1,048,576
//   [9995264)    Zb    : B*N*C bf16     = 8,388,608   (Z = W@x, [B,N,C])
// total 18,383,872
// ---------------------------------------------------------------------------

static __device__ __forceinline__ short f2bf(float v) {
    __hip_bfloat16 h = __float2bfloat16(v);   // RNE
    return __builtin_bit_cast(short, h);
}

// Small prep: W -> bf16; fold BN affine; xyz -> SoA float4 with |p|^2
__global__ __launch_bounds__(256) void small_prep_kernel(
    const float* __restrict__ xyz, const float* __restrict__ W,
    const float* __restrict__ gamma, const float* __restrict__ beta,
    const float* __restrict__ rmean, const float* __restrict__ rvar,
    short* __restrict__ Wb, float* __restrict__ scale, float* __restrict__ bias,
    float4* __restrict__ pts)
{
    const int t = blockIdx.x * 256 + threadIdx.x;   // grid covers B*N = 32768
    if (t < CCH * CCH) Wb[t] = f2bf(W[t]);
    if (t < CCH) {
        const float s = gamma[t] / sqrtf(rvar[t] + 1e-5f);
        scale[t] = s;
        bias[t]  = beta[t] - rmean[t] * s;
    }
    {
        #pragma clang fp contract(off)
        const float px = xyz[3 * t + 0];
        const float py = xyz[3 * t + 1];
        const float pz = xyz[3 * t + 2];
        const float s  = px * px + py * py + pz * pz;   // matches ref s = sum(xyz*xyz)
        pts[t] = make_float4(px, py, pz, s);
    }
}

#define PK_(h, l) ((((unsigned long long)(h)) << 32) | (unsigned long long)(l))

// KNN v4 (R4/R12-verified dense kernel, byte-identical — 87 us, VALUBusy
// ~87%). Buffered top-k with bitonic flush:
//  - manual A/C double-buffered candidate registers (no rotation moves)
//  - block 0 special case: first 16 candidates bitonic-sorted directly
//    into the list (kills tau=inf warm-up appends/flushes)
// Selection semantics == reference top_k: 16 smallest by (d2, j) lex,
// emitted in lex order. See R2 comments for the exactness argument.
__global__ __launch_bounds__(256) void knn_kernel(
    const float4* __restrict__ pts, unsigned short* __restrict__ knn)
{
    const int lane = threadIdx.x & 63;
    const int wid  = threadIdx.x >> 6;
    const int g    = lane >> 4;                 // group (query) 0..3
    const int s    = lane & 15;                 // slot within group
    const int wq   = blockIdx.x * 16 + wid * 4; // first query of this wave
    const int b    = wq >> 12;                  // 4 queries never cross a batch
    const int i    = (wq & 4095) + g;           // this lane's query
    const float4* pb = pts + (b << 12);

    const float4 q = pb[i];                     // group-uniform

    const unsigned SENT_HI = 0xFF7FFFFFu;       // mono(+3.4e38)
    const unsigned SENT_LO = 0xFFFFFFFFu;

    unsigned lhi = SENT_HI, llo = SENT_LO;      // sorted top-16 list (asc)
    float bufD = 0.f;                           // survivor buffer (slot s)
    int   bufJ = 0;
    int   cnt  = 0;                             // valid entries (group-uniform)
    float tau  = 3.4e38f;
    const int gsh = g << 4;

    // ascending bitonic sort of (hi,lo) keys across the 16 group lanes
    auto sort16 = [&](unsigned& hi, unsigned& lo) {
        #define CE_(K, J, OFF) { \
            const unsigned ohi = (unsigned)__builtin_amdgcn_ds_swizzle((int)hi, OFF); \
            const unsigned olo = (unsigned)__builtin_amdgcn_ds_swizzle((int)lo, OFF); \
            const bool olt = PK_(ohi, olo) < PK_(hi, lo); \
            const bool sel = (((s & (J)) == 0) == ((s & (K)) == 0)); \
            const bool tk  = sel ? olt : !olt; \
            hi = tk ? ohi : hi; lo = tk ? olo : lo; }
        CE_(2, 1, 0x041F)
        CE_(4, 2, 0x081F)  CE_(4, 1, 0x041F)
        CE_(8, 4, 0x101F)  CE_(8, 2, 0x081F)  CE_(8, 1, 0x041F)
        CE_(16, 8, 0x201F) CE_(16, 4, 0x101F) CE_(16, 2, 0x081F) CE_(16, 1, 0x041F)
        #undef CE_
    };

    // tau = inv-mono(list[15].hi)  (broadcast slot 15 within each 16-group)
    auto refresh_tau = [&]() {
        const unsigned thi = (unsigned)__builtin_amdgcn_ds_swizzle((int)lhi, 0x01F0);
        tau = __uint_as_float((thi & 0x80000000u) ? (thi & 0x7FFFFFFFu) : ~thi);
    };

    auto flush = [&]() {
        // build keys from buffer; invalid slots -> sentinel
        const unsigned u = __float_as_uint(bufD);
        unsigned khi = (u & 0x80000000u) ? ~u : (u | 0x80000000u);
        unsigned klo = (unsigned)bufJ;
        const bool inval = (s >= cnt);
        khi = inval ? SENT_HI : khi;
        klo = inval ? SENT_LO : klo;
        sort16(khi, klo);
        // merge with list: reverse buffer, elementwise min, 4 clean stages
        {
            const unsigned rhi = (unsigned)__builtin_amdgcn_ds_swizzle((int)khi, 0x3C1F);
            const unsigned rlo = (unsigned)__builtin_amdgcn_ds_swizzle((int)klo, 0x3C1F);
            const bool rlt = PK_(rhi, rlo) < PK_(lhi, llo);
            lhi = rlt ? rhi : lhi; llo = rlt ? rlo : llo;
        }
        #define MC_(J, OFF) { \
            const unsigned ohi = (unsigned)__builtin_amdgcn_ds_swizzle((int)lhi, OFF); \
            const unsigned olo = (unsigned)__builtin_amdgcn_ds_swizzle((int)llo, OFF); \
            const bool olt = PK_(ohi, olo) < PK_(lhi, llo); \
            const bool tk  = ((s & (J)) == 0) ? olt : !olt; \
            lhi = tk ? ohi : lhi; llo = tk ? olo : llo; }
        MC_(8, 0x201F) MC_(4, 0x101F) MC_(2, 0x081F) MC_(1, 0x041F)
        #undef MC_
        refresh_tau();
        cnt = 0;
    };

    // filter + parallel append for one 16-candidate sub-chunk
    #define SUB_(DD, C, JB) { \
        const unsigned long long mask = __ballot((DD) < tau); \
        if (mask) { \
            const unsigned sub = (unsigned)((mask >> gsh) & 0xFFFFull); \
            const int m = __popc(sub); \
            if (__any(cnt + m > 15)) flush(); \
            const bool surv = (sub >> s) & 1u; \
            const int rank  = __popc(sub & ((1u << s) - 1u)); \
            const int dest  = surv ? (cnt + rank) : 15;   /* slot 15 free when m<16 */ \
            const int addr  = (gsh | dest) << 2; \
            const int nd = __builtin_amdgcn_ds_permute(addr, __float_as_int(DD)); \
            const int nj = __builtin_amdgcn_ds_permute(addr, (JB) + ((C) << 4) + s); \
            const bool got = (s >= cnt) & (s < cnt + m); \
            bufD = got ? __int_as_float(nd) : bufD; \
            bufJ = got ? nj : bufJ; \
            cnt += m; \
        } }

    // process one 64-candidate block (4 sub-chunks of 16)
    auto process = [&](const float4& p0, const float4& p1,
                       const float4& p2, const float4& p3, const int jbase) {
        float dd0, dd1, dd2, dd3;
        {
            #pragma clang fp contract(off)
            dd0 = (q.w + p0.w) - 2.0f * (q.x * p0.x + q.y * p0.y + q.z * p0.z);
            dd1 = (q.w + p1.w) - 2.0f * (q.x * p1.x + q.y * p1.y + q.z * p1.z);
            dd2 = (q.w + p2.w) - 2.0f * (q.x * p2.x + q.y * p2.y + q.z * p2.z);
            dd3 = (q.w + p3.w) - 2.0f * (q.x * p3.x + q.y * p3.y + q.z * p3.z);
        }
        SUB_(dd0, 0, jbase)
        SUB_(dd1, 1, jbase)
        SUB_(dd2, 2, jbase)
        SUB_(dd3, 3, jbase)
    };

    const float4* lp = pb + s;
    // block 0 into A, block 1 into C
    float4 a0 = lp[0],  a1 = lp[16],  a2 = lp[32],  a3 = lp[48];
    float4 c0 = lp[64], c1 = lp[80],  c2 = lp[96],  c3 = lp[112];

    // ---- special block 0: sort first sub-chunk (j = s) directly into list
    {
        float dd0, dd1, dd2, dd3;
        {
            #pragma clang fp contract(off)
            dd0 = (q.w + a0.w) - 2.0f * (q.x * a0.x + q.y * a0.y + q.z * a0.z);
            dd1 = (q.w + a1.w) - 2.0f * (q.x * a1.x + q.y * a1.y + q.z * a1.z);
            dd2 = (q.w + a2.w) - 2.0f * (q.x * a2.x + q.y * a2.y + q.z * a2.z);
            dd3 = (q.w + a3.w) - 2.0f * (q.x * a3.x + q.y * a3.y + q.z * a3.z);
        }
        const unsigned u = __float_as_uint(dd0);
        lhi = (u & 0x80000000u) ? ~u : (u | 0x80000000u);
        llo = (unsigned)s;                      // j = s for sub-chunk 0
        sort16(lhi, llo);
        refresh_tau();
        SUB_(dd1, 1, 0)
        SUB_(dd2, 2, 0)
        SUB_(dd3, 3, 0)
    }

    // ---- main loop: blocks 1..62 double-buffered, 63 peeled
    #pragma unroll 1
    for (int t = 0; t < 31; ++t) {
        const int blk = 1 + 2 * t;              // C holds block blk
        const float4* p2 = lp + (blk + 1) * 64; // prefetch blk+1 into A
        a0 = p2[0]; a1 = p2[16]; a2 = p2[32]; a3 = p2[48];
        process(c0, c1, c2, c3, blk * 64);
        const float4* p3 = lp + (blk + 2) * 64; // prefetch blk+2 into C (max 63)
        c0 = p3[0]; c1 = p3[16]; c2 = p3[32]; c3 = p3[48];
        process(a0, a1, a2, a3, (blk + 1) * 64);
    }
    process(c0, c1, c2, c3, 63 * 64);           // C holds block 63
    #undef SUB_

    flush();                                    // drain remaining buffer

    unsigned short* o = knn + ((((size_t)b << 12) + i) << 4);
    o[s] = (unsigned short)llo;                 // j of s-th smallest (d2, j)
}

// Fused transpose + GEMM: x [B,C,N] fp32 -> (bf16 LDS tile) -> Z = W@x,
// Zb bf16 [B*N, C]. Eliminates the xTb global round-trip (16 MB) + a launch.
// Block = 64 n-rows x 128 c. Phase 1: stage W in LDS (pitch 136, proven) +
// load x tile via float4 (consecutive lanes -> consecutive cc: coalesced
// 4x256B/wave) and convert into tile[nn][cc] pitch 136 (stores: consecutive
// cc shorts -> 2-way bank = free). Phase 2: byte-identical zgemm MFMA loop,
// A-fragments from LDS tile (16 rows x stride-68-dword reads -> 2-way = free;
// verified mappings: A m=lane&15 k=(lane>>4)*8+j; B n=lane&15; C/D col=lane&15,
// row=(lane>>4)*4+reg). LDS 52.2 KB; grid 512 blocks = 2/CU, occupancy
// unaffected.
__global__ __launch_bounds__(256) void tzgemm_kernel(
    const float* __restrict__ x, const short* __restrict__ Wb,
    short* __restrict__ Zb)
{
    __shared__ short tile[64 * 136];             // [nn][cc] bf16
    __shared__ short sW[CCH * 136];
    const int tid  = threadIdx.x;
    const int lane = tid & 63;
    const int wid  = tid >> 6;
    const int kl   = lane & 15;
    const int q8   = (lane >> 4) * 8;
    const int b    = blockIdx.x >> 6;            // 8 batches
    const int nt   = blockIdx.x & 63;            // 64 n-tiles of 64

    #pragma unroll
    for (int it = 0; it < 8; ++it) {             // stage W: 16384 elems
        const int e = (it * 256 + tid) * 8;
        const int r = e >> 7, c = e & 127;
        *(bf16x8*)(sW + r * 136 + c) = *(const bf16x8*)(Wb + e);
    }
    #pragma unroll
    for (int it = 0; it < 8; ++it) {             // x tile: 64n x 128c fp32
        const int idx = it * 256 + tid;          // 0..2047
        const int cc  = idx & 127;
        const int nf  = idx >> 7;                // float4 index along n
        const float4 v = *(const float4*)(
            x + (size_t)(b * CCH + cc) * NPTS + nt * 64 + nf * 4);
        tile[(nf * 4 + 0) * 136 + cc] = f2bf(v.x);
        tile[(nf * 4 + 1) * 136 + cc] = f2bf(v.y);
        tile[(nf * 4 + 2) * 136 + cc] = f2bf(v.z);
        tile[(nf * 4 + 3) * 136 + cc] = f2bf(v.w);
    }
    __syncthreads();

    const f32x4 zero = {0.f, 0.f, 0.f, 0.f};
    f32x4 acc[8];
    #pragma unroll
    for (int t = 0; t < 8; ++t) acc[t] = zero;

    #pragma unroll
    for (int kk = 0; kk < 4; ++kk) {
        const bf16x8 a = *(const bf16x8*)(tile + (wid * 16 + kl) * 136 + kk * 32 + q8);
        #pragma unroll
        for (int t = 0; t < 8; ++t) {
            const bf16x8 bf = *(const bf16x8*)(sW + (t * 16 + kl) * 136 + kk * 32 + q8);
            acc[t] = __builtin_amdgcn_mfma_f32_16x16x32_bf16(a, bf, acc[t], 0, 0, 0);
        }
    }

    const int rbase = blockIdx.x * 64 + wid * 16 + (lane >> 4) * 4;
    #pragma unroll
    for (int t = 0; t < 8; ++t)
        #pragma unroll
        for (int r = 0; r < 4; ++r)
            Zb[(size_t)(rbase + r) * CCH + t * 16 + kl] = f2bf(acc[t][r]);
}

// Gather + BN + ReLU + max-over-16, then coalesced store via LDS transpose.
// Block = 16 points; wave w handles 4 points serially; lane l covers channels
// 2l, 2l+1. Neighbor indices loaded as 2x uint4 up front so the 16 Zb row
// loads issue independently.
__global__ __launch_bounds__(256) void gmax_kernel(
    const short* __restrict__ Zb, const unsigned short* __restrict__ knn,
    const float* __restrict__ scale, const float* __restrict__ bias,
    float* __restrict__ out)
{
    __shared__ float sm[16][132];
    const int lane = threadIdx.x & 63;
    const int wid  = threadIdx.x >> 6;
    const int n0   = blockIdx.x * 16;           // flat point base (B*N)
    const int b    = blockIdx.x >> 8;           // 256 blocks per batch
    const float s0 = scale[2 * lane],   s1 = scale[2 * lane + 1];
    const float t0 = bias[2 * lane],    t1 = bias[2 * lane + 1];

    for (int p = 0; p < 4; ++p) {
        const int n = n0 + wid * 4 + p;         // flat
        const unsigned short* kr = knn + (size_t)n * 16;
        int ridx[16];
        {
            const uint4 ka = *(const uint4*)kr;        // 32B-aligned
            const uint4 kb = *(const uint4*)(kr + 8);
            ridx[0] = ka.x & 0xFFFF; ridx[1] = ka.x >> 16;
            ridx[2] = ka.y & 0xFFFF; ridx[3] = ka.y >> 16;
            ridx[4] = ka.z & 0xFFFF; ridx[5] = ka.z >> 16;
            ridx[6] = ka.w & 0xFFFF; ridx[7] = ka.w >> 16;
            ridx[8]  = kb.x & 0xFFFF; ridx[9]  = kb.x >> 16;
            ridx[10] = kb.y & 0xFFFF; ridx[11] = kb.y >> 16;
            ridx[12] = kb.z & 0xFFFF; ridx[13] = kb.z >> 16;
            ridx[14] = kb.w & 0xFFFF; ridx[15] = kb.w >> 16;
        }
        float m0 = 0.f, m1 = 0.f;               // relu floor
        #pragma unroll
        for (int k = 0; k < 16; ++k) {
            const unsigned v = *(const unsigned*)(
                Zb + ((size_t)(b * NPTS + ridx[k])) * CCH + 2 * lane);
            const float z0 = __uint_as_float(v << 16);
            const float z1 = __uint_as_float(v & 0xFFFF0000u);
            m0 = fmaxf(m0, s0 * z0 + t0);
            m1 = fmaxf(m1, s1 * z1 + t1);
        }
        sm[wid * 4 + p][2 * lane]     = m0;
        sm[wid * 4 + p][2 * lane + 1] = m1;
    }
    __syncthreads();

    const int c    = threadIdx.x & 127;
    const int half = threadIdx.x >> 7;
    float v[8];
    #pragma unroll
    for (int i = 0; i < 8; ++i) v[i] = sm[half * 8 + i][c];
    float4 f0 = {v[0], v[1], v[2], v[3]};
    float4 f1 = {v[4], v[5], v[6], v[7]};
    float* op = out + ((size_t)(b * CCH + c)) * NPTS + (n0 & 4095) + half * 8;
    *(float4*)op       = f0;
    *(float4*)(op + 4) = f1;
}

extern "C" void kernel_launch(void* const* d_in, const int* in_sizes, int n_in,
                              void* d_out, int out_size, void* d_ws, size_t ws_size,
                              hipStream_t stream)
{
    const float* xyz   = (const float*)d_in[0];
    const float* x     = (const float*)d_in[1];
    const float* W     = (const float*)d_in[2];
    const float* gamma = (const float*)d_in[3];
    const float* beta  = (const float*)d_in[4];
    const float* rmean = (const float*)d_in[5];
    const float* rvar  = (const float*)d_in[6];
    float* out = (float*)d_out;

    char* ws = (char*)d_ws;
    short*          Wb    = (short*)(ws + 8388608);
    float*          scale = (float*)(ws + 8421376);
    float*          bias  = (float*)(ws + 8421888);
    float4*         pts   = (float4*)(ws + 8422400);
    unsigned short* knn   = (unsigned short*)(ws + 8946688);
    short*          Zb    = (short*)(ws + 9995264);

    small_prep_kernel<<<BATCH * NPTS / 256, 256, 0, stream>>>(
        xyz, W, gamma, beta, rmean, rvar, Wb, scale, bias, pts);
    knn_kernel<<<BATCH * NPTS / 16, 256, 0, stream>>>(pts, knn);
    tzgemm_kernel<<<BATCH * 64, 256, 0, stream>>>(x, Wb, Zb);
    gmax_kernel<<<BATCH * NPTS / 16, 256, 0, stream>>>(Zb, knn, scale, bias, out);
}

// Round 14
// 107.079 us; speedup vs baseline: 1.4226x; 1.0345x over previous
//
#include <hip/hip_runtime.h>
#include <hip/hip_bf16.h>

// Problem constants (fixed by the reference)
#define BATCH 8
#define NPTS  4096      // N
#define CCH   128      // C
#define KNN_K 16       // K

typedef __attribute__((ext_vector_type(8))) short  bf16x8;  // 8 bf16 = 4 VGPRs
typedef __attribute__((ext_vector_type(4))) float  f32x4;   // MFMA acc

// ---------------------------------------------------------------------------
// ws layout (bytes):
//   [0)          (unused; was xTb)      = 8,388,608
//   [8388608)    Wb    : C*C  bf16      =    32,768
//   [8421376)    scale : C fp32         =       512
//   [8421888)    bias  : C fp32         =       512
//   [8422400)    pts   : B*N float4(x,y,z,s) = 524,288
//   [8946688)    knn   : B*N*K u16      = 1,048,576
//   [9995264)    Zb    : B*N*C bf16     = 8,388,608   (Z = W@x, [B,N,C])
// total 18,383,872
// ---------------------------------------------------------------------------

static __device__ __forceinline__ short f2bf(float v) {
    __hip_bfloat16 h = __float2bfloat16(v);   // RNE
    return __builtin_bit_cast(short, h);
}

// Small prep: W -> bf16; fold BN affine; xyz -> SoA float4 with |p|^2
__global__ __launch_bounds__(256) void small_prep_kernel(
    const float* __restrict__ xyz, const float* __restrict__ W,
    const float* __restrict__ gamma, const float* __restrict__ beta,
    const float* __restrict__ rmean, const float* __restrict__ rvar,
    short* __restrict__ Wb, float* __restrict__ scale, float* __restrict__ bias,
    float4* __restrict__ pts)
{
    const int t = blockIdx.x * 256 + threadIdx.x;   // grid covers B*N = 32768
    if (t < CCH * CCH) Wb[t] = f2bf(W[t]);
    if (t < CCH) {
        const float s = gamma[t] / sqrtf(rvar[t] + 1e-5f);
        scale[t] = s;
        bias[t]  = beta[t] - rmean[t] * s;
    }
    {
        #pragma clang fp contract(off)
        const float px = xyz[3 * t + 0];
        const float py = xyz[3 * t + 1];
        const float pz = xyz[3 * t + 2];
        const float s  = px * px + py * py + pz * pz;   // matches ref s = sum(xyz*xyz)
        pts[t] = make_float4(px, py, pz, s);
    }
}

#define PK_(h, l) ((((unsigned long long)(h)) << 32) | (unsigned long long)(l))

// KNN v4 (R4/R12/R13-verified dense kernel — 87 us, VALUBusy ~87%) + XCD
// batch-affinity swizzle: bid = (blockIdx%8)*256 + blockIdx/8 maps all blocks
// of batch k onto XCD k (round-robin dispatch), so each XCD's L2 hot set is
// one batch's pts (64 KB) + knn slice instead of all 8 batches interleaved
// (FETCH was 2.17 GB/dispatch of L2 refills). Bijective remap; selection
// machinery byte-identical. Buffered top-k with bitonic flush; semantics ==
// reference top_k (16 smallest by (d2, j) lex, emitted in lex order).
__global__ __launch_bounds__(256) void knn_kernel(
    const float4* __restrict__ pts, unsigned short* __restrict__ knn)
{
    const int bid  = (blockIdx.x & 7) * 256 + (blockIdx.x >> 3);  // XCD swizzle
    const int lane = threadIdx.x & 63;
    const int wid  = threadIdx.x >> 6;
    const int g    = lane >> 4;                 // group (query) 0..3
    const int s    = lane & 15;                 // slot within group
    const int wq   = bid * 16 + wid * 4;        // first query of this wave
    const int b    = wq >> 12;                  // 4 queries never cross a batch
    const int i    = (wq & 4095) + g;           // this lane's query
    const float4* pb = pts + (b << 12);

    const float4 q = pb[i];                     // group-uniform

    const unsigned SENT_HI = 0xFF7FFFFFu;       // mono(+3.4e38)
    const unsigned SENT_LO = 0xFFFFFFFFu;

    unsigned lhi = SENT_HI, llo = SENT_LO;      // sorted top-16 list (asc)
    float bufD = 0.f;                           // survivor buffer (slot s)
    int   bufJ = 0;
    int   cnt  = 0;                             // valid entries (group-uniform)
    float tau  = 3.4e38f;
    const int gsh = g << 4;

    // ascending bitonic sort of (hi,lo) keys across the 16 group lanes
    auto sort16 = [&](unsigned& hi, unsigned& lo) {
        #define CE_(K, J, OFF) { \
            const unsigned ohi = (unsigned)__builtin_amdgcn_ds_swizzle((int)hi, OFF); \
            const unsigned olo = (unsigned)__builtin_amdgcn_ds_swizzle((int)lo, OFF); \
            const bool olt = PK_(ohi, olo) < PK_(hi, lo); \
            const bool sel = (((s & (J)) == 0) == ((s & (K)) == 0)); \
            const bool tk  = sel ? olt : !olt; \
            hi = tk ? ohi : hi; lo = tk ? olo : lo; }
        CE_(2, 1, 0x041F)
        CE_(4, 2, 0x081F)  CE_(4, 1, 0x041F)
        CE_(8, 4, 0x101F)  CE_(8, 2, 0x081F)  CE_(8, 1, 0x041F)
        CE_(16, 8, 0x201F) CE_(16, 4, 0x101F) CE_(16, 2, 0x081F) CE_(16, 1, 0x041F)
        #undef CE_
    };

    // tau = inv-mono(list[15].hi)  (broadcast slot 15 within each 16-group)
    auto refresh_tau = [&]() {
        const unsigned thi = (unsigned)__builtin_amdgcn_ds_swizzle((int)lhi, 0x01F0);
        tau = __uint_as_float((thi & 0x80000000u) ? (thi & 0x7FFFFFFFu) : ~thi);
    };

    auto flush = [&]() {
        // build keys from buffer; invalid slots -> sentinel
        const unsigned u = __float_as_uint(bufD);
        unsigned khi = (u & 0x80000000u) ? ~u : (u | 0x80000000u);
        unsigned klo = (unsigned)bufJ;
        const bool inval = (s >= cnt);
        khi = inval ? SENT_HI : khi;
        klo = inval ? SENT_LO : klo;
        sort16(khi, klo);
        // merge with list: reverse buffer, elementwise min, 4 clean stages
        {
            const unsigned rhi = (unsigned)__builtin_amdgcn_ds_swizzle((int)khi, 0x3C1F);
            const unsigned rlo = (unsigned)__builtin_amdgcn_ds_swizzle((int)klo, 0x3C1F);
            const bool rlt = PK_(rhi, rlo) < PK_(lhi, llo);
            lhi = rlt ? rhi : lhi; llo = rlt ? rlo : llo;
        }
        #define MC_(J, OFF) { \
            const unsigned ohi = (unsigned)__builtin_amdgcn_ds_swizzle((int)lhi, OFF); \
            const unsigned olo = (unsigned)__builtin_amdgcn_ds_swizzle((int)llo, OFF); \
            const bool olt = PK_(ohi, olo) < PK_(lhi, llo); \
            const bool tk  = ((s & (J)) == 0) ? olt : !olt; \
            lhi = tk ? ohi : lhi; llo = tk ? olo : llo; }
        MC_(8, 0x201F) MC_(4, 0x101F) MC_(2, 0x081F) MC_(1, 0x041F)
        #undef MC_
        refresh_tau();
        cnt = 0;
    };

    // filter + parallel append for one 16-candidate sub-chunk
    #define SUB_(DD, C, JB) { \
        const unsigned long long mask = __ballot((DD) < tau); \
        if (mask) { \
            const unsigned sub = (unsigned)((mask >> gsh) & 0xFFFFull); \
            const int m = __popc(sub); \
            if (__any(cnt + m > 15)) flush(); \
            const bool surv = (sub >> s) & 1u; \
            const int rank  = __popc(sub & ((1u << s) - 1u)); \
            const int dest  = surv ? (cnt + rank) : 15;   /* slot 15 free when m<16 */ \
            const int addr  = (gsh | dest) << 2; \
            const int nd = __builtin_amdgcn_ds_permute(addr, __float_as_int(DD)); \
            const int nj = __builtin_amdgcn_ds_permute(addr, (JB) + ((C) << 4) + s); \
            const bool got = (s >= cnt) & (s < cnt + m); \
            bufD = got ? __int_as_float(nd) : bufD; \
            bufJ = got ? nj : bufJ; \
            cnt += m; \
        } }

    // process one 64-candidate block (4 sub-chunks of 16)
    auto process = [&](const float4& p0, const float4& p1,
                       const float4& p2, const float4& p3, const int jbase) {
        float dd0, dd1, dd2, dd3;
        {
            #pragma clang fp contract(off)
            dd0 = (q.w + p0.w) - 2.0f * (q.x * p0.x + q.y * p0.y + q.z * p0.z);
            dd1 = (q.w + p1.w) - 2.0f * (q.x * p1.x + q.y * p1.y + q.z * p1.z);
            dd2 = (q.w + p2.w) - 2.0f * (q.x * p2.x + q.y * p2.y + q.z * p2.z);
            dd3 = (q.w + p3.w) - 2.0f * (q.x * p3.x + q.y * p3.y + q.z * p3.z);
        }
        SUB_(dd0, 0, jbase)
        SUB_(dd1, 1, jbase)
        SUB_(dd2, 2, jbase)
        SUB_(dd3, 3, jbase)
    };

    const float4* lp = pb + s;
    // block 0 into A, block 1 into C
    float4 a0 = lp[0],  a1 = lp[16],  a2 = lp[32],  a3 = lp[48];
    float4 c0 = lp[64], c1 = lp[80],  c2 = lp[96],  c3 = lp[112];

    // ---- special block 0: sort first sub-chunk (j = s) directly into list
    {
        float dd0, dd1, dd2, dd3;
        {
            #pragma clang fp contract(off)
            dd0 = (q.w + a0.w) - 2.0f * (q.x * a0.x + q.y * a0.y + q.z * a0.z);
            dd1 = (q.w + a1.w) - 2.0f * (q.x * a1.x + q.y * a1.y + q.z * a1.z);
            dd2 = (q.w + a2.w) - 2.0f * (q.x * a2.x + q.y * a2.y + q.z * a2.z);
            dd3 = (q.w + a3.w) - 2.0f * (q.x * a3.x + q.y * a3.y + q.z * a3.z);
        }
        const unsigned u = __float_as_uint(dd0);
        lhi = (u & 0x80000000u) ? ~u : (u | 0x80000000u);
        llo = (unsigned)s;                      // j = s for sub-chunk 0
        sort16(lhi, llo);
        refresh_tau();
        SUB_(dd1, 1, 0)
        SUB_(dd2, 2, 0)
        SUB_(dd3, 3, 0)
    }

    // ---- main loop: blocks 1..62 double-buffered, 63 peeled
    #pragma unroll 1
    for (int t = 0; t < 31; ++t) {
        const int blk = 1 + 2 * t;              // C holds block blk
        const float4* p2 = lp + (blk + 1) * 64; // prefetch blk+1 into A
        a0 = p2[0]; a1 = p2[16]; a2 = p2[32]; a3 = p2[48];
        process(c0, c1, c2, c3, blk * 64);
        const float4* p3 = lp + (blk + 2) * 64; // prefetch blk+2 into C (max 63)
        c0 = p3[0]; c1 = p3[16]; c2 = p3[32]; c3 = p3[48];
        process(a0, a1, a2, a3, (blk + 1) * 64);
    }
    process(c0, c1, c2, c3, 63 * 64);           // C holds block 63
    #undef SUB_

    flush();                                    // drain remaining buffer

    unsigned short* o = knn + ((((size_t)b << 12) + i) << 4);
    o[s] = (unsigned short)llo;                 // j of s-th smallest (d2, j)
}

// Fused transpose + GEMM: x [B,C,N] fp32 -> (bf16 LDS tile) -> Z = W@x,
// Zb bf16 [B*N, C]. (R13-verified.) Block = 64 n-rows x 128 c.
__global__ __launch_bounds__(256) void tzgemm_kernel(
    const float* __restrict__ x, const short* __restrict__ Wb,
    short* __restrict__ Zb)
{
    __shared__ short tile[64 * 136];             // [nn][cc] bf16
    __shared__ short sW[CCH * 136];
    const int tid  = threadIdx.x;
    const int lane = tid & 63;
    const int wid  = tid >> 6;
    const int kl   = lane & 15;
    const int q8   = (lane >> 4) * 8;
    const int b    = blockIdx.x >> 6;            // 8 batches
    const int nt   = blockIdx.x & 63;            // 64 n-tiles of 64

    #pragma unroll
    for (int it = 0; it < 8; ++it) {             // stage W: 16384 elems
        const int e = (it * 256 + tid) * 8;
        const int r = e >> 7, c = e & 127;
        *(bf16x8*)(sW + r * 136 + c) = *(const bf16x8*)(Wb + e);
    }
    #pragma unroll
    for (int it = 0; it < 8; ++it) {             // x tile: 64n x 128c fp32
        const int idx = it * 256 + tid;          // 0..2047
        const int cc  = idx & 127;
        const int nf  = idx >> 7;                // float4 index along n
        const float4 v = *(const float4*)(
            x + (size_t)(b * CCH + cc) * NPTS + nt * 64 + nf * 4);
        tile[(nf * 4 + 0) * 136 + cc] = f2bf(v.x);
        tile[(nf * 4 + 1) * 136 + cc] = f2bf(v.y);
        tile[(nf * 4 + 2) * 136 + cc] = f2bf(v.z);
        tile[(nf * 4 + 3) * 136 + cc] = f2bf(v.w);
    }
    __syncthreads();

    const f32x4 zero = {0.f, 0.f, 0.f, 0.f};
    f32x4 acc[8];
    #pragma unroll
    for (int t = 0; t < 8; ++t) acc[t] = zero;

    #pragma unroll
    for (int kk = 0; kk < 4; ++kk) {
        const bf16x8 a = *(const bf16x8*)(tile + (wid * 16 + kl) * 136 + kk * 32 + q8);
        #pragma unroll
        for (int t = 0; t < 8; ++t) {
            const bf16x8 bf = *(const bf16x8*)(sW + (t * 16 + kl) * 136 + kk * 32 + q8);
            acc[t] = __builtin_amdgcn_mfma_f32_16x16x32_bf16(a, bf, acc[t], 0, 0, 0);
        }
    }

    const int rbase = blockIdx.x * 64 + wid * 16 + (lane >> 4) * 4;
    #pragma unroll
    for (int t = 0; t < 8; ++t)
        #pragma unroll
        for (int r = 0; r < 4; ++r)
            Zb[(size_t)(rbase + r) * CCH + t * 16 + kl] = f2bf(acc[t][r]);
}

// Gather + BN + ReLU + max-over-16, then coalesced store via LDS transpose.
// v3: XCD batch-affinity swizzle (same remap as knn): batch k's blocks land
// on XCD k so the gather works against an L2-resident 1.1 MB hot set
// (Zb slice + knn slice) instead of 9 MB interleaved across all XCDs.
__global__ __launch_bounds__(256) void gmax_kernel(
    const short* __restrict__ Zb, const unsigned short* __restrict__ knn,
    const float* __restrict__ scale, const float* __restrict__ bias,
    float* __restrict__ out)
{
    __shared__ float sm[16][132];
    const int bid  = (blockIdx.x & 7) * 256 + (blockIdx.x >> 3);  // XCD swizzle
    const int lane = threadIdx.x & 63;
    const int wid  = threadIdx.x >> 6;
    const int n0   = bid * 16;                  // flat point base (B*N)
    const int b    = bid >> 8;                  // 256 blocks per batch
    const float s0 = scale[2 * lane],   s1 = scale[2 * lane + 1];
    const float t0 = bias[2 * lane],    t1 = bias[2 * lane + 1];

    for (int p = 0; p < 4; ++p) {
        const int n = n0 + wid * 4 + p;         // flat
        const unsigned short* kr = knn + (size_t)n * 16;
        int ridx[16];
        {
            const uint4 ka = *(const uint4*)kr;        // 32B-aligned
            const uint4 kb = *(const uint4*)(kr + 8);
            ridx[0] = ka.x & 0xFFFF; ridx[1] = ka.x >> 16;
            ridx[2] = ka.y & 0xFFFF; ridx[3] = ka.y >> 16;
            ridx[4] = ka.z & 0xFFFF; ridx[5] = ka.z >> 16;
            ridx[6] = ka.w & 0xFFFF; ridx[7] = ka.w >> 16;
            ridx[8]  = kb.x & 0xFFFF; ridx[9]  = kb.x >> 16;
            ridx[10] = kb.y & 0xFFFF; ridx[11] = kb.y >> 16;
            ridx[12] = kb.z & 0xFFFF; ridx[13] = kb.z >> 16;
            ridx[14] = kb.w & 0xFFFF; ridx[15] = kb.w >> 16;
        }
        float m0 = 0.f, m1 = 0.f;               // relu floor
        #pragma unroll
        for (int k = 0; k < 16; ++k) {
            const unsigned v = *(const unsigned*)(
                Zb + ((size_t)(b * NPTS + ridx[k])) * CCH + 2 * lane);
            const float z0 = __uint_as_float(v << 16);
            const float z1 = __uint_as_float(v & 0xFFFF0000u);
            m0 = fmaxf(m0, s0 * z0 + t0);
            m1 = fmaxf(m1, s1 * z1 + t1);
        }
        sm[wid * 4 + p][2 * lane]     = m0;
        sm[wid * 4 + p][2 * lane + 1] = m1;
    }
    __syncthreads();

    const int c    = threadIdx.x & 127;
    const int half = threadIdx.x >> 7;
    float v[8];
    #pragma unroll
    for (int i = 0; i < 8; ++i) v[i] = sm[half * 8 + i][c];
    float4 f0 = {v[0], v[1], v[2], v[3]};
    float4 f1 = {v[4], v[5], v[6], v[7]};
    float* op = out + ((size_t)(b * CCH + c)) * NPTS + (n0 & 4095) + half * 8;
    *(float4*)op       = f0;
    *(float4*)(op + 4) = f1;
}

extern "C" void kernel_launch(void* const* d_in, const int* in_sizes, int n_in,
                              void* d_out, int out_size, void* d_ws, size_t ws_size,
                              hipStream_t stream)
{
    const float* xyz   = (const float*)d_in[0];
    const float* x     = (const float*)d_in[1];
    const float* W     = (const float*)d_in[2];
    const float* gamma = (const float*)d_in[3];
    const float* beta  = (const float*)d_in[4];
    const float* rmean = (const float*)d_in[5];
    const float* rvar  = (const float*)d_in[6];
    float* out = (float*)d_out;

    char* ws = (char*)d_ws;
    short*          Wb    = (short*)(ws + 8388608);
    float*          scale = (float*)(ws + 8421376);
    float*          bias  = (float*)(ws + 8421888);
    float4*         pts   = (float4*)(ws + 8422400);
    unsigned short* knn   = (unsigned short*)(ws + 8946688);
    short*          Zb    = (short*)(ws + 9995264);

    small_prep_kernel<<<BATCH * NPTS / 256, 256, 0, stream>>>(
        xyz, W, gamma, beta, rmean, rvar, Wb, scale, bias, pts);
    knn_kernel<<<BATCH * NPTS / 16, 256, 0, stream>>>(pts, knn);
    tzgemm_kernel<<<BATCH * 64, 256, 0, stream>>>(x, Wb, Zb);
    gmax_kernel<<<BATCH * NPTS / 16, 256, 0, stream>>>(Zb, knn, scale, bias, out);
}